// Round 2
// baseline (421.309 us; speedup 1.0000x reference)
//
#include <hip/hip_runtime.h>
#include <math.h>

// R6: same bf16x3 MFMA algorithm as R5; schedule restructured.
//  - R5 issued the x-prefetch immediately before __syncthreads -> the
//    compiler's vmcnt(0)-before-barrier drained a full HBM latency 64x/block.
//    Now commit+issue sit at the TOP of the iteration; the MFMA phase covers
//    the load latency and the barrier drain is ~free.
//  - R5 ran 1 wave/SIMD (256 blocks x 4 waves). Now 512 threads (8 waves,
//    2 waves/SIMD) with 32tok x 32exp wave tiles: W L2 traffic unchanged
//    (each W line still read by exactly 2 waves), staging VALU per thread
//    halved, second wave hides residual stalls.
//  - Epilogue merge scratch padded to stride 9 (was a 64-way bank conflict).

#define T_TOKENS 16384
#define D_K      4096
#define N_EXP    128
#define TOK_BLK  64
#define KSTEP    64
#define NITER    (D_K / KSTEP)     // 64

typedef float  f32x4  __attribute__((ext_vector_type(4)));
typedef short  bf16x8 __attribute__((ext_vector_type(8)));
typedef float  fragc  __attribute__((ext_vector_type(4)));

__device__ __forceinline__ unsigned short bf16_rne(float f) {
    unsigned u = __float_as_uint(f);
    u += 0x7FFFu + ((u >> 16) & 1u);          // round-to-nearest-even
    return (unsigned short)(u >> 16);
}
__device__ __forceinline__ float bf16f(unsigned short h) {
    return __uint_as_float(((unsigned)h) << 16);
}

// A-fragment LDS offset with XOR swizzle (proven in R5): line L = G*64 + l
// holds 8 bf16 (16 B); off16 = L ^ (((L>>3)^G)&7) is bijective per 8-line
// stripe and spreads both ds_write_b128 and ds_read_b128 across banks.
__device__ __forceinline__ int a_off(int G, int l) {
    const int L  = G * 64 + l;
    const int sw = ((L >> 3) ^ G) & 7;
    return (L << 4) ^ (sw << 4);
}

// ---------------------------------------------------------------------------
// prep_w: W [128][4096] f32 -> fragment-linear Wh, Wl bf16 (unchanged, ~5 us).
__global__ __launch_bounds__(256)
void prep_w(const float* __restrict__ W,
            short* __restrict__ wh, short* __restrict__ wl) {
    const int gid = blockIdx.x * 256 + threadIdx.x;   // 0..65535 lines
    const int l   = gid & 63;
    const int ntk = gid >> 6;                         // kbG*8 + nt
    const int e   = ((ntk & 7) << 4) + (l & 15);
    const int k   = ((ntk >> 3) << 5) + ((l >> 4) << 3);
    const float* src = W + (size_t)e * D_K + k;
    const f32x4 v0 = *(const f32x4*)src;
    const f32x4 v1 = *(const f32x4*)(src + 4);
    bf16x8 hv, lv;
#pragma unroll
    for (int j = 0; j < 8; ++j) {
        const float f = (j < 4) ? v0[j] : v1[j - 4];
        const unsigned short hh = bf16_rne(f);
        hv[j] = (short)hh;
        lv[j] = (short)bf16_rne(f - bf16f(hh));
    }
    *(bf16x8*)(wh + (size_t)gid * 8) = hv;
    *(bf16x8*)(wl + (size_t)gid * 8) = lv;
}

// ---------------------------------------------------------------------------
// Fused GEMM + softmax + top-2. 256 blocks x 512 thr (8 waves, 2/SIMD).
// Block: 64 tok x 128 exp. Wave tile: 32 tok (2 Mtiles) x 32 exp (2 Ntiles).
#define LOGSTRIDE 140
#define MERGE_OFF (64 * LOGSTRIDE * 4)            // 35840
#define SMEM_SZ   (MERGE_OFF + 64 * 8 * 9 * 4)    // 54272 (GEMM bufs alias: 32 KB)

__global__ __launch_bounds__(512, 2)
void router_mfma(const float* __restrict__ x,
                 const short* __restrict__ wh,
                 const short* __restrict__ wl,
                 const float* __restrict__ bvec,
                 float* __restrict__ out) {
    __shared__ __align__(16) char smem[SMEM_SZ];

    const int tid  = threadIdx.x;
    const int lane = tid & 63;
    const int w    = tid >> 6;
    const int wm   = w >> 2;          // 0..1 : token half (32 tok)
    const int wn   = w & 3;           // 0..3 : expert quarter (32 exp)
    const int g    = blockIdx.x;

    // staging: 512 threads cover 64 tok x 64 k in ONE round (8 floats each)
    const int s_tok = tid >> 3;       // 0..63
    const int s_kc8 = tid & 7;        // 0..7
    const float* xsrc = x + (size_t)(g * TOK_BLK + s_tok) * D_K + s_kc8 * 8;
    const int G_s   = ((s_kc8 >> 2) << 2) + (s_tok >> 4);
    const int l_s   = (s_tok & 15) | ((s_kc8 & 3) << 4);
    const int off_s = a_off(G_s, l_s);

    f32x4 ld0, ld1;
    auto issue = [&](int t) {
        const float* p = xsrc + (size_t)t * KSTEP;
        ld0 = *(const f32x4*)p;
        ld1 = *(const f32x4*)(p + 4);
    };
    auto commit = [&](int bufbase) {
        bf16x8 hv, lv;
#pragma unroll
        for (int j = 0; j < 8; ++j) {
            const float f = (j < 4) ? ld0[j] : ld1[j - 4];
            const unsigned short hh = bf16_rne(f);
            hv[j] = (short)hh;
            lv[j] = (short)bf16_rne(f - bf16f(hh));
        }
        *(bf16x8*)(smem + bufbase + off_s)        = hv;
        *(bf16x8*)(smem + bufbase + 8192 + off_s) = lv;
    };

    // wave-uniform W bases: line = (kbG*8 + wn*2 + nt)*64 + lane, 8 elems/line
    const short* base_h = wh + ((size_t)(wn * 2) * 64 + lane) * 8;
    const short* base_l = wl + ((size_t)(wn * 2) * 64 + lane) * 8;

    fragc acc[2][2];
#pragma unroll
    for (int mi = 0; mi < 2; ++mi)
#pragma unroll
        for (int nt = 0; nt < 2; ++nt)
            acc[mi][nt] = (fragc){0.f, 0.f, 0.f, 0.f};

    issue(0);
    commit(0);            // buf0 (one-time exposed latency)
    issue(1);
    __syncthreads();

    for (int t = 0; t < NITER; ++t) {
        const int cur = (t & 1) << 14;    // 16 KB per buffer (h 8K + l 8K)

        // ---- prefetch phase (top of iter: latency covered by MFMA below) ----
        if (t + 1 < NITER) {
            commit(cur ^ (1 << 14));      // tile t+1 -> other buffer
            if (t + 2 < NITER) issue(t + 2);
        }

        // ---- hoist all W-fragment loads for this iter (L2-hot) ----
        bf16x8 bh[2][2], bl[2][2];
#pragma unroll
        for (int kb = 0; kb < 2; ++kb) {
            const size_t kofs = (size_t)(2 * t + kb) * 4096;
#pragma unroll
            for (int nt = 0; nt < 2; ++nt) {
                bh[kb][nt] = *(const bf16x8*)(base_h + kofs + nt * 512);
                bl[kb][nt] = *(const bf16x8*)(base_l + kofs + nt * 512);
            }
        }

        // ---- MFMA phase ----
#pragma unroll
        for (int kb = 0; kb < 2; ++kb) {
            bf16x8 ah[2], al[2];
#pragma unroll
            for (int mi = 0; mi < 2; ++mi) {
                const int off = a_off(kb * 4 + wm * 2 + mi, lane);
                ah[mi] = *(const bf16x8*)(smem + cur + off);
                al[mi] = *(const bf16x8*)(smem + cur + 8192 + off);
            }
#pragma unroll
            for (int mi = 0; mi < 2; ++mi)
#pragma unroll
                for (int nt = 0; nt < 2; ++nt) {
                    acc[mi][nt] = __builtin_amdgcn_mfma_f32_16x16x32_bf16(
                        ah[mi], bh[kb][nt], acc[mi][nt], 0, 0, 0);
                    acc[mi][nt] = __builtin_amdgcn_mfma_f32_16x16x32_bf16(
                        al[mi], bh[kb][nt], acc[mi][nt], 0, 0, 0);
                    acc[mi][nt] = __builtin_amdgcn_mfma_f32_16x16x32_bf16(
                        ah[mi], bl[kb][nt], acc[mi][nt], 0, 0, 0);
                }
        }
        __syncthreads();
    }

    // ---- epilogue: logits -> LDS, fused softmax + top-2 + renorm ----
    float* lg = (float*)smem;
#pragma unroll
    for (int mi = 0; mi < 2; ++mi) {
        const int row0 = wm * 32 + mi * 16 + ((lane >> 4) << 2);
#pragma unroll
        for (int nt = 0; nt < 2; ++nt) {
            const int col = wn * 32 + nt * 16 + (lane & 15);
#pragma unroll
            for (int j = 0; j < 4; ++j)
                lg[(row0 + j) * LOGSTRIDE + col] = acc[mi][nt][j];
        }
    }
    __syncthreads();

    // 8 threads per token scan 16 experts each (index-ascending, strict > :
    // first-occurrence tie-break, matching jax top_k)
    const int tok = tid & 63;
    const int q   = tid >> 6;             // wave-uniform segment 0..7
    const float* lrow = lg + tok * LOGSTRIDE + q * 16;
    const float* brow = bvec + q * 16;
    float v1 = -INFINITY, v2 = -INFINITY;
    int   i1 = 0, i2 = 0;
#pragma unroll
    for (int c = 0; c < 16; ++c) {
        const float lv = lrow[c] + brow[c];
        if (lv > v1)      { v2 = v1; i2 = i1; v1 = lv; i1 = c; }
        else if (lv > v2) { v2 = lv; i2 = c; }
    }
    float Z = 0.f;
#pragma unroll
    for (int c = 0; c < 16; ++c) Z += expf(lrow[c] + brow[c] - v1);

    float* mrow = (float*)(smem + MERGE_OFF) + (tok * 8 + q) * 9;
    mrow[0] = v1; mrow[1] = (float)(q * 16 + i1);
    mrow[2] = v2; mrow[3] = (float)(q * 16 + i2);
    mrow[4] = Z;
    __syncthreads();

    if (tid < 64) {
        const float* m0 = (float*)(smem + MERGE_OFF) + tid * 72;
        float V1 = m0[0], I1 = m0[1], V2 = m0[2], I2 = m0[3], Zs = m0[4];
#pragma unroll
        for (int q2 = 1; q2 < 8; ++q2) {
            const float* mq = m0 + q2 * 9;
            const float a1 = mq[0], ai1 = mq[1], a2 = mq[2], ai2 = mq[3], Zq = mq[4];
            const float M  = fmaxf(V1, a1);
            Zs = Zs * expf(V1 - M) + Zq * expf(a1 - M);
            if (a1 > V1)      { V2 = V1; I2 = I1; V1 = a1; I1 = ai1; }
            else if (a1 > V2) { V2 = a1; I2 = ai1; }
            if (a2 > V2)      { V2 = a2; I2 = ai2; }
        }
        const float p1 = 1.0f / Zs;               // exp(V1-V1)/Z
        const float p2 = expf(V2 - V1) / Zs;
        const float s  = p1 + p2 + 1e-8f;
        const int tokG = g * TOK_BLK + tid;
        float2* oidx  = (float2*)out;
        float2* oprob = ((float2*)out) + T_TOKENS;
        oidx[tokG]  = make_float2(I1, I2);
        oprob[tokG] = make_float2(p1 / s, p2 / s);
    }
}

extern "C" void kernel_launch(void* const* d_in, const int* in_sizes, int n_in,
                              void* d_out, int out_size, void* d_ws, size_t ws_size,
                              hipStream_t stream) {
    (void)in_sizes; (void)n_in; (void)out_size; (void)ws_size;
    const float* x = (const float*)d_in[0];
    const float* W = (const float*)d_in[1];
    const float* b = (const float*)d_in[2];
    float* out = (float*)d_out;
    short* wh = (short*)d_ws;                         // 1 MB
    short* wl = (short*)d_ws + (size_t)N_EXP * D_K;   // 1 MB

    prep_w<<<dim3(256), dim3(256), 0, stream>>>(W, wh, wl);
    router_mfma<<<dim3(T_TOKENS / TOK_BLK), dim3(512), 0, stream>>>(x, wh, wl, b, out);
}